// Round 5
// baseline (235.255 us; speedup 1.0000x reference)
//
#include <hip/hip_runtime.h>

#define HH 64
#define VV 50257
#define BB 32
#define LL 4096

constexpr float LN_EPS_F = 1e-5f;
constexpr float DELTA_EPS_F = 1e-6f;

constexpr int CS = 64;       // chunk size (steps per chunk)
constexpr int NG = LL / CS;  // 64 chunks per batch

typedef float f32x4 __attribute__((ext_vector_type(4)));
typedef float f32x2 __attribute__((ext_vector_type(2)));
typedef short bf16x8 __attribute__((ext_vector_type(8)));
union U16x8 { uint4 u; bf16x8 v; unsigned short s[8]; };

__device__ __forceinline__ unsigned short f2bf(float f) {
  union { float f; unsigned u; } v; v.f = f;
  unsigned r = v.u + 0x7fff + ((v.u >> 16) & 1);  // RNE
  return (unsigned short)(r >> 16);
}

// v_cvt_pk_bf16_f32: lo16 = bf16(a), hi16 = bf16(b); RNE — bit-identical to f2bf.
__device__ __forceinline__ unsigned cvt_pk_bf16(float a, float b) {
  unsigned r;
  asm("v_cvt_pk_bf16_f32 %0, %1, %2" : "=v"(r) : "v"(a), "v"(b));
  return r;
}

// hi/lo split for a pair: hp = packed bf16 hi parts, lp = packed bf16 residuals.
__device__ __forceinline__ void split2(float a, float b, unsigned& hp, unsigned& lp) {
  hp = cvt_pk_bf16(a, b);
  float ha = __uint_as_float(hp << 16);
  float hb = __uint_as_float(hp & 0xffff0000u);
  lp = cvt_pk_bf16(a - ha, b - hb);
}

// ---------------- DPP wave reduction (sum of 64 lanes -> lane 63) ----------------
template <int CTRL>
__device__ __forceinline__ float dpp_add(float x) {
  int t = __builtin_amdgcn_update_dpp(0, __float_as_int(x), CTRL, 0xF, 0xF, true);
  return x + __int_as_float(t);
}

__device__ __forceinline__ float wave_sum_lane63(float x) {
  x = dpp_add<0x111>(x);
  x = dpp_add<0x112>(x);
  x = dpp_add<0x114>(x);
  x = dpp_add<0x118>(x);
  x = dpp_add<0x142>(x);
  x = dpp_add<0x143>(x);
  return x;
}

__device__ __forceinline__ float readlane_f(float x, int lane) {
  return __int_as_float(__builtin_amdgcn_readlane(__float_as_int(x), lane));
}

// ---------------- Kernel 0: bf16 weight prep ----------------
__global__ __launch_bounds__(256) void prep_kernel(
    const float* __restrict__ w1, const float* __restrict__ w2,
    unsigned short* __restrict__ w1b, unsigned short* __restrict__ w2b) {
  int i = blockIdx.x * 256 + threadIdx.x;  // 0..16383
  if (i < 8192) {
    int jj = i >> 6, h = i & 63;
    w1b[i] = f2bf(w1[h * 128 + jj]);
  } else {
    int k = i - 8192;
    int h = k >> 7, jj = k & 127;
    w2b[k] = f2bf(w2[jj * 64 + h]);
  }
}

// ---------------- Kernel 1: encoder via bf16 MFMA — LDS overlay (28 KB) ----------
__global__ __launch_bounds__(64, 1) void encoder_kernel(
    const int* __restrict__ seq, const float* __restrict__ embed,
    const unsigned short* __restrict__ w1b, const float* __restrict__ b1,
    const unsigned short* __restrict__ w2b, const float* __restrict__ b2,
    const float* __restrict__ ln_g, const float* __restrict__ ln_b,
    float* __restrict__ h_all, float* __restrict__ beta) {
  __shared__ __align__(16) char pool[26624];  // e_l(9216) + act_l(17408); x_l(16640) aliases
  unsigned short (*e_l)[72] = reinterpret_cast<unsigned short (*)[72]>(pool);
  unsigned short (*act_l)[136] = reinterpret_cast<unsigned short (*)[136]>(pool + 9216);
  float (*x_l)[65] = reinterpret_cast<float (*)[65]>(pool);
  __shared__ float2 gb_l[64];
  __shared__ float b1_l[128], b2_l[64];

  int lane = threadIdx.x;
  int q = lane >> 4, l = lane & 15;
  int base = blockIdx.x * 64;
  int s = seq[base + lane];

  {
    const float4* ep = reinterpret_cast<const float4*>(embed + (size_t)s * HH);
#pragma unroll
    for (int i = 0; i < 8; ++i) {
      float4 va = ep[2 * i], vb = ep[2 * i + 1];
      uint4 u;
      u.x = cvt_pk_bf16(va.x, va.y);
      u.y = cvt_pk_bf16(va.z, va.w);
      u.z = cvt_pk_bf16(vb.x, vb.y);
      u.w = cvt_pk_bf16(vb.z, vb.w);
      *(uint4*)&e_l[lane][8 * i] = u;
    }
  }
  gb_l[lane] = make_float2(ln_g[lane], ln_b[lane]);
  b1_l[lane] = b1[lane];
  b1_l[64 + lane] = b1[64 + lane];
  b2_l[lane] = b2[lane];

  bf16x8 af1[8][2];
#pragma unroll
  for (int mi = 0; mi < 8; ++mi)
#pragma unroll
    for (int ks = 0; ks < 2; ++ks) {
      U16x8 t;
      t.u = *(const uint4*)(w1b + (mi * 16 + l) * 64 + ks * 32 + q * 8);
      af1[mi][ks] = t.v;
    }

  __syncthreads();

  f32x4 acc1[8][4];
#pragma unroll
  for (int mi = 0; mi < 8; ++mi)
#pragma unroll
    for (int nt = 0; nt < 4; ++nt) acc1[mi][nt] = (f32x4){0.f, 0.f, 0.f, 0.f};

#pragma unroll
  for (int ks = 0; ks < 2; ++ks) {
    bf16x8 bfr[4];
#pragma unroll
    for (int nt = 0; nt < 4; ++nt) {
      U16x8 t;
      t.u = *(const uint4*)&e_l[nt * 16 + l][ks * 32 + q * 8];
      bfr[nt] = t.v;
    }
#pragma unroll
    for (int mi = 0; mi < 8; ++mi)
#pragma unroll
      for (int nt = 0; nt < 4; ++nt)
        acc1[mi][nt] = __builtin_amdgcn_mfma_f32_16x16x32_bf16(
            af1[mi][ks], bfr[nt], acc1[mi][nt], 0, 0, 0);
  }

#pragma unroll
  for (int mi = 0; mi < 8; ++mi)
#pragma unroll
    for (int nt = 0; nt < 4; ++nt) {
      int tok = nt * 16 + l;
      int jj0 = mi * 16 + q * 4;
      float v0 = fmaxf(acc1[mi][nt][0] + b1_l[jj0 + 0], 0.f);
      float v1 = fmaxf(acc1[mi][nt][1] + b1_l[jj0 + 1], 0.f);
      float v2 = fmaxf(acc1[mi][nt][2] + b1_l[jj0 + 2], 0.f);
      float v3 = fmaxf(acc1[mi][nt][3] + b1_l[jj0 + 3], 0.f);
      uint2 u;
      u.x = cvt_pk_bf16(v0, v1);
      u.y = cvt_pk_bf16(v2, v3);
      *(uint2*)&act_l[tok][jj0] = u;
    }

  bf16x8 bf2[4][4];
#pragma unroll
  for (int nt = 0; nt < 4; ++nt)
#pragma unroll
    for (int ks = 0; ks < 4; ++ks) {
      U16x8 t;
      t.u = *(const uint4*)(w2b + (nt * 16 + l) * 128 + ks * 32 + q * 8);
      bf2[nt][ks] = t.v;
    }

  __syncthreads();

  f32x4 acc2[4][4];
#pragma unroll
  for (int mt = 0; mt < 4; ++mt)
#pragma unroll
    for (int nt = 0; nt < 4; ++nt) acc2[mt][nt] = (f32x4){0.f, 0.f, 0.f, 0.f};

#pragma unroll
  for (int ks = 0; ks < 4; ++ks) {
    bf16x8 afr[4];
#pragma unroll
    for (int mt = 0; mt < 4; ++mt) {
      U16x8 t;
      t.u = *(const uint4*)&act_l[mt * 16 + l][ks * 32 + q * 8];
      afr[mt] = t.v;
    }
#pragma unroll
    for (int mt = 0; mt < 4; ++mt)
#pragma unroll
      for (int nt = 0; nt < 4; ++nt)
        acc2[mt][nt] = __builtin_amdgcn_mfma_f32_16x16x32_bf16(
            afr[mt], bf2[nt][ks], acc2[mt][nt], 0, 0, 0);
  }

  __syncthreads();  // act_l/e_l reads complete before x_l (alias) writes

#pragma unroll
  for (int mt = 0; mt < 4; ++mt)
#pragma unroll
    for (int nt = 0; nt < 4; ++nt) {
      int h = nt * 16 + l;
#pragma unroll
      for (int r = 0; r < 4; ++r) {
        int tok = mt * 16 + q * 4 + r;
        x_l[tok][h] = acc2[mt][nt][r] + b2_l[h];
      }
    }

  __syncthreads();

  float x[HH];
#pragma unroll
  for (int h = 0; h < HH; ++h) x[h] = x_l[lane][h];
  {
    const float4* ep = reinterpret_cast<const float4*>(embed + (size_t)s * HH);
#pragma unroll
    for (int i = 0; i < 16; ++i) {
      float4 v = ep[i];
      x[4 * i + 0] += v.x; x[4 * i + 1] += v.y;
      x[4 * i + 2] += v.z; x[4 * i + 3] += v.w;
    }
  }
  float sum = 0.f;
#pragma unroll
  for (int h = 0; h < HH; ++h) sum += x[h];
  float mu = sum * (1.f / HH);
  float vs = 0.f;
#pragma unroll
  for (int h = 0; h < HH; ++h) { float dx = x[h] - mu; vs = fmaf(dx, dx, vs); }
  float rstd = rsqrtf(vs * (1.f / HH) + LN_EPS_F);

  float ss = 0.f;
#pragma unroll
  for (int h = 0; h < HH; ++h) {
    float2 gb = gb_l[h];
    float o = fmaf((x[h] - mu) * rstd, gb.x, gb.y);
    ss = fmaf(o, o, ss);
    x[h] = o;
  }
  float4* hp = reinterpret_cast<float4*>(h_all + (size_t)(base + lane) * HH);
#pragma unroll
  for (int i = 0; i < 16; ++i)
    hp[i] = make_float4(x[4 * i + 0], x[4 * i + 1], x[4 * i + 2], x[4 * i + 3]);
  beta[base + lane] = 1.f / (ss + DELTA_EPS_F);
}

// ---------------- Kernel 2: Gram + m-recurrence + materialized N^T ----------------
// r13: VALU-issue diet + occupancy (r12 post-mortem: ~15K VALU-issue cycles/block
// at 1 wave/SIMD, 60% unhidden stall).
//   * v_cvt_pk_bf16_f32 (2 values/instr, RNE == f2bf bitwise) replaces all
//     f2bf+pack chains: ~8 -> ~3 instr/value across ~260 values.
//   * m kept as f32x2[32]; rank-4 update uses __builtin_elementwise_fma ->
//     v_pk_fma_f32 (halves the 2016-FMA issue). Static indices only.
//   * LDS 37120 -> 27136 (6 blocks/CU = 1.5 waves/SIMD): pB replaced by a
//     half-K buffer pBh[2][64][32] (8192 B, XOR-swizzle byte^=(row&7)<<4)
//     overlaid on dead Glp; N runs as 2 uniform halves of 48 MFMAs each.
// Numerics bit-identical to r12 (same RNE bits, same fma ops).
// LDS: [pA 18432][Glp 8448 / pBh 8192 overlay][bl 256] = 27136.
__global__ __launch_bounds__(64, 1) void gram_n_kernel(
    const float* __restrict__ h_all, const float* __restrict__ beta,
    float* __restrict__ Ng) {
  __shared__ __align__(16) char smem[27136];
  unsigned short (*pA)[64][72] = reinterpret_cast<unsigned short (*)[64][72]>(smem);  // 18432 B (K^T)
  float* Glp = reinterpret_cast<float*>(smem + 18432);                                // 8448 B
  char* pBh0 = smem + 18432;                                                          // 8192 B overlay (2 planes x 4096)
  float* bl = reinterpret_cast<float*>(smem + 26880);                                 // 256 B

  int c = blockIdx.x, b = blockIdx.y, lane = threadIdx.x;
  int q = lane >> 4, l = lane & 15;
  const float* src = h_all + ((size_t)b * LL + c * CS) * HH;

  // ---- Gram frags direct from global (no LDS staging), cvt_pk split
  bf16x8 ah[2][4], al_[2][4];
#pragma unroll
  for (int ks = 0; ks < 2; ++ks)
#pragma unroll
    for (int i = 0; i < 4; ++i) {
      const float* p = src + (i * 16 + l) * 64 + ks * 32 + q * 8;
      float4 va = *(const float4*)p, vb = *(const float4*)(p + 4);
      U16x8 hi, lo;
      split2(va.x, va.y, hi.u.x, lo.u.x);
      split2(va.z, va.w, hi.u.y, lo.u.y);
      split2(vb.x, vb.y, hi.u.z, lo.u.z);
      split2(vb.z, vb.w, hi.u.w, lo.u.w);
      ah[ks][i] = hi.v; al_[ks][i] = lo.v;
    }
  // t = L-1 is not a key: zero row 63 of K in the frags (held by l==15, i==3)
  if (c == NG - 1 && l == 15) {
#pragma unroll
    for (int ks = 0; ks < 2; ++ks) {
      ah[ks][3] = (bf16x8){0, 0, 0, 0, 0, 0, 0, 0};
      al_[ks][3] = (bf16x8){0, 0, 0, 0, 0, 0, 0, 0};
    }
  }

  bl[lane] = beta[(size_t)b * LL + c * CS + lane];

  // ---- m column loads issued BEFORE Gram compute (latency overlaps MFMAs)
  f32x2 m2[32];
#pragma unroll
  for (int t = 0; t < 32; ++t)
    m2[t] = (f32x2){src[(2 * t) * 64 + lane], src[(2 * t + 1) * 64 + lane]};
  if (c == NG - 1) m2[31].y = 0.f;

  // ---- Gram via split-bf16 MFMA (symmetric: lower tiles only, 60 MFMAs)
  f32x4 acc[4][4];
#pragma unroll
  for (int mi = 0; mi < 4; ++mi)
#pragma unroll
    for (int nt = 0; nt <= mi; ++nt) acc[mi][nt] = (f32x4){0.f, 0.f, 0.f, 0.f};

#pragma unroll
  for (int ks = 0; ks < 2; ++ks)
#pragma unroll
    for (int mi = 0; mi < 4; ++mi)
#pragma unroll
      for (int nt = 0; nt <= mi; ++nt) {
        acc[mi][nt] = __builtin_amdgcn_mfma_f32_16x16x32_bf16(ah[ks][mi], ah[ks][nt], acc[mi][nt], 0, 0, 0);
        acc[mi][nt] = __builtin_amdgcn_mfma_f32_16x16x32_bf16(ah[ks][mi], al_[ks][nt], acc[mi][nt], 0, 0, 0);
        acc[mi][nt] = __builtin_amdgcn_mfma_f32_16x16x32_bf16(al_[ks][mi], ah[ks][nt], acc[mi][nt], 0, 0, 0);
      }

  // ---- packed triangular Gl write (UNSCALED G; only t < s entries).
  // Row s=4g+i offsets: off(4g)=4g(2g+1); off(4g+i)=8g(g+1)+4(g+1)(i-1), i>=1.
#pragma unroll
  for (int mi = 0; mi < 4; ++mi) {
    int gg = 4 * mi + q;
    int e1 = 8 * gg * (gg + 1);
    int o0 = 4 * gg * (2 * gg + 1);
    int o1 = e1;
    int o2 = e1 + 4 * (gg + 1);
    int o3 = e1 + 8 * (gg + 1);
#pragma unroll
    for (int nt = 0; nt < mi; ++nt) {
      int t = nt * 16 + l;
      Glp[o0 + t] = acc[mi][nt][0];
      Glp[o1 + t] = acc[mi][nt][1];
      Glp[o2 + t] = acc[mi][nt][2];
      Glp[o3 + t] = acc[mi][nt][3];
    }
    {
      int t = mi * 16 + l;
      if (l < 4 * q)     Glp[o0 + t] = acc[mi][mi][0];
      if (l < 4 * q + 1) Glp[o1 + t] = acc[mi][mi][1];
      if (l < 4 * q + 2) Glp[o2 + t] = acc[mi][mi][2];
      if (l < 4 * q + 3) Glp[o3 + t] = acc[mi][mi][3];
    }
  }

  // ---- build colS = K^T rows (bf16 hi/lo) into pA from m INITIAL
#pragma unroll
  for (int i = 0; i < 16; ++i) {
    unsigned h0, l0, h1, l1;
    split2(m2[2 * i].x, m2[2 * i].y, h0, l0);
    split2(m2[2 * i + 1].x, m2[2 * i + 1].y, h1, l1);
    *(uint2*)&pA[0][lane][4 * i] = make_uint2(h0, h1);
    *(uint2*)&pA[1][lane][4 * i] = make_uint2(l0, l1);
  }
  __syncthreads();  // Glp writes visible before recurrence reads

  // ---- rank-4 grouped m-recurrence (exact f32, pk-fma pairs), beta folded.
#pragma unroll
  for (int g = 15; g >= 0; --g) {
    int e1 = 8 * g * (g + 1);
    int o0 = 4 * g * (2 * g + 1);
    int o1 = e1;
    int o2 = e1 + 4 * (g + 1);
    int o3 = e1 + 8 * (g + 1);
    float4 C1 = *(const float4*)(Glp + o1 + 4 * g);  // row 4g+1 (x valid)
    float4 C2 = *(const float4*)(Glp + o2 + 4 * g);  // row 4g+2 (x,y valid)
    float4 C3 = *(const float4*)(Glp + o3 + 4 * g);  // row 4g+3 (x,y,z valid)
    float4 B4 = *(const float4*)(bl + 4 * g);        // beta[4g..4g+3] (uniform)

    float t3 = B4.w * m2[2 * g + 1].y;
    float v2 = fmaf(-C3.z, t3, m2[2 * g + 1].x);
    float t2 = B4.z * v2;
    float v1 = fmaf(-C2.y, t2, fmaf(-C3.y, t3, m2[2 * g].y));
    float t1 = B4.y * v1;
    float v0 = fmaf(-C1.x, t1, fmaf(-C2.x, t2, fmaf(-C3.x, t3, m2[2 * g].x)));
    float t0 = B4.x * v0;
    m2[2 * g] = (f32x2){t0, t1};
    m2[2 * g + 1] = (f32x2){t2, t3};
    f32x2 n0 = {-t0, -t0}, n1 = {-t1, -t1}, n2 = {-t2, -t2}, n3 = {-t3, -t3};

#pragma unroll
    for (int j = 0; j < g; ++j) {
      float4 R0 = *(const float4*)(Glp + o0 + 4 * j);
      float4 R1 = *(const float4*)(Glp + o1 + 4 * j);
      float4 R2 = *(const float4*)(Glp + o2 + 4 * j);
      float4 R3 = *(const float4*)(Glp + o3 + 4 * j);
      f32x2 a = m2[2 * j], d = m2[2 * j + 1];
      a = __builtin_elementwise_fma((f32x2){R0.x, R0.y}, n0, a);
      a = __builtin_elementwise_fma((f32x2){R1.x, R1.y}, n1, a);
      a = __builtin_elementwise_fma((f32x2){R2.x, R2.y}, n2, a);
      a = __builtin_elementwise_fma((f32x2){R3.x, R3.y}, n3, a);
      d = __builtin_elementwise_fma((f32x2){R0.z, R0.w}, n0, d);
      d = __builtin_elementwise_fma((f32x2){R1.z, R1.w}, n1, d);
      d = __builtin_elementwise_fma((f32x2){R2.z, R2.w}, n2, d);
      d = __builtin_elementwise_fma((f32x2){R3.z, R3.w}, n3, d);
      m2[2 * j] = a; m2[2 * j + 1] = d;
    }
  }
  // m2[] now holds m~ = beta_t * m_final[t] — the B operand N needs.

  __syncthreads();  // all Glp/bl reads done before pBh (overlay) writes

  // ---- N in 2 K-halves: write half of (m~)^T (swizzled), 48 MFMAs, repeat.
  f32x4 acc2[4][4];
#pragma unroll
  for (int mi = 0; mi < 4; ++mi)
#pragma unroll
    for (int nt = 0; nt < 4; ++nt) acc2[mi][nt] = (f32x4){0.f, 0.f, 0.f, 0.f};

#pragma unroll
  for (int hf = 0; hf < 2; ++hf) {
    // write pBh rows (row = h' = lane, cols t = hf*32..hf*32+31), XOR-swizzled
#pragma unroll
    for (int i2 = 0; i2 < 8; ++i2) {
      int tt = hf * 16 + 2 * i2;  // m2 index base: t = hf*32 + 4*i2
      unsigned h0, l0, h1, l1;
      split2(m2[tt].x, m2[tt].y, h0, l0);
      split2(m2[tt + 1].x, m2[tt + 1].y, h1, l1);
      unsigned boff = (unsigned)((lane * 64 + i2 * 8) ^ ((lane & 7) << 4));
      *(uint2*)(pBh0 + boff) = make_uint2(h0, h1);
      *(uint2*)(pBh0 + 4096 + boff) = make_uint2(l0, l1);
    }
    __syncthreads();  // pBh writes visible (1-wave: compiles to waitcnt)

    bf16x8 kh[4], kl_[4], bh[4], blo[4];
#pragma unroll
    for (int i = 0; i < 4; ++i) {
      U16x8 t;
      t.u = *(const uint4*)&pA[0][i * 16 + l][hf * 32 + q * 8]; kh[i] = t.v;
      t.u = *(const uint4*)&pA[1][i * 16 + l][hf * 32 + q * 8]; kl_[i] = t.v;
      unsigned bro = (unsigned)((((16 * i + l) * 64) + q * 16) ^ ((l & 7) << 4));
      t.u = *(const uint4*)(pBh0 + bro);        bh[i] = t.v;
      t.u = *(const uint4*)(pBh0 + 4096 + bro); blo[i] = t.v;
    }
#pragma unroll
    for (int mi = 0; mi < 4; ++mi)
#pragma unroll
      for (int nt = 0; nt < 4; ++nt) {
        acc2[mi][nt] = __builtin_amdgcn_mfma_f32_16x16x32_bf16(kh[mi], bh[nt], acc2[mi][nt], 0, 0, 0);
        acc2[mi][nt] = __builtin_amdgcn_mfma_f32_16x16x32_bf16(kh[mi], blo[nt], acc2[mi][nt], 0, 0, 0);
        acc2[mi][nt] = __builtin_amdgcn_mfma_f32_16x16x32_bf16(kl_[mi], bh[nt], acc2[mi][nt], 0, 0, 0);
      }
    __syncthreads();  // half-hf B-frag reads done before next half's overwrite
  }

  // store TRANSPOSED: Ng[j*64 + h] = N[h][j]  (float4 over h)
  float* np = Ng + (((size_t)b * NG + c) << 12);
#pragma unroll
  for (int mi = 0; mi < 4; ++mi)
#pragma unroll
    for (int nt = 0; nt < 4; ++nt) {
      int h0 = mi * 16 + q * 4, hp = nt * 16 + l;
      float4 v;
      v.x = ((h0 + 0 == hp) ? 1.f : 0.f) - acc2[mi][nt][0];
      v.y = ((h0 + 1 == hp) ? 1.f : 0.f) - acc2[mi][nt][1];
      v.z = ((h0 + 2 == hp) ? 1.f : 0.f) - acc2[mi][nt][2];
      v.w = ((h0 + 3 == hp) ? 1.f : 0.f) - acc2[mi][nt][3];
      *(float4*)&np[hp * 64 + h0] = v;
    }
}

// ---------------- Kernel 3: boundary — LDS double-buffered matvec (unchanged) -----
__global__ __launch_bounds__(64, 1) void boundary_kernel(
    const float* __restrict__ h_all, const float* __restrict__ Ng,
    const int* __restrict__ read_pos_p, float* __restrict__ Qg) {
  __shared__ __align__(16) float nt0[64 * 64];
  __shared__ __align__(16) float nt1[64 * 64];
  __shared__ __align__(16) float ql[64];

  int b = blockIdx.x, lane = threadIdx.x;
  int rpv = read_pos_p[0];
  int pos = rpv < 0 ? rpv + LL : rpv;
  float Q = h_all[((size_t)b * LL + pos) * HH + lane];

  const float* Nb = Ng + ((size_t)b * NG << 12);

  auto load_chunk = [&](float* buf, int c) {
    const float* g = Nb + ((size_t)c << 12);
#pragma unroll
    for (int i = 0; i < 16; ++i)
      __builtin_amdgcn_global_load_lds(
          (const __attribute__((address_space(1))) unsigned*)(g + i * 256 + lane * 4),
          (__attribute__((address_space(3))) unsigned*)(buf + i * 256), 16, 0, 0);
  };

  auto step = [&](const float* buf, int c, bool last) {
    if (last) __builtin_amdgcn_s_waitcnt(0x0F70);  // vmcnt(0)
    else      __builtin_amdgcn_s_waitcnt(0x4F70);  // vmcnt(16)
    Qg[((size_t)b * NG + c) * HH + lane] = Q;
    ql[lane] = Q;
    float a0 = 0.f, a1 = 0.f, a2 = 0.f, a3 = 0.f;
#pragma unroll
    for (int j = 0; j < 64; j += 4) {
      float4 q4 = *(const float4*)&ql[j];  // uniform LDS broadcast
      a0 = fmaf(buf[(j + 0) * 64 + lane], q4.x, a0);
      a1 = fmaf(buf[(j + 1) * 64 + lane], q4.y, a1);
      a2 = fmaf(buf[(j + 2) * 64 + lane], q4.z, a2);
      a3 = fmaf(buf[(j + 3) * 64 + lane], q4.w, a3);
    }
    Q = (a0 + a1) + (a2 + a3);
  };

  load_chunk(nt1, NG - 1);
  load_chunk(nt0, NG - 2);

#pragma unroll 1
  for (int c = NG - 1; c >= 1; c -= 2) {
    step(nt1, c, false);
    __builtin_amdgcn_s_waitcnt(0xC07F);  // lgkmcnt(0)
    if (c >= 3) load_chunk(nt1, c - 2);
    step(nt0, c - 1, c == 1);
    __builtin_amdgcn_s_waitcnt(0xC07F);
    if (c >= 3) load_chunk(nt0, c - 3);
  }
}

// ---------------- Kernel 4 (phase 3): parallel within-chunk r accumulation -------
__global__ __launch_bounds__(64, 1) void chunk_scan_kernel(
    const float* __restrict__ h_all, const float* __restrict__ beta,
    const float* __restrict__ Qg, float* __restrict__ rc) {
  int c = blockIdx.x, b = blockIdx.y, j = threadIdx.x;
  const float* hb = h_all + (size_t)b * LL * HH;
  const float* betab = beta + (size_t)b * LL;

  float P = Qg[((size_t)b * NG + c) * HH + j];
  float r = 0.f;

  float kk[CS];
#pragma unroll
  for (int i = 0; i < CS; ++i) kk[i] = hb[((size_t)(c * CS + i)) * HH + j];
  float bv = betab[c * CS + j];

  bool last = (c == NG - 1);
#pragma unroll
  for (int i = CS - 1; i >= 0; --i) {
    float k = kk[i];
    float bt = readlane_f(bv, i);
    float m = k * P;
    float s = wave_sum_lane63(m);
    float d = readlane_f(s, 63);
    if (i == CS - 1 && last) d = 0.f;
    r = fmaf(d, k, r);
    P = fmaf(-(bt * d), k, P);
  }
  rc[((size_t)b * NG + c) * HH + j] = r;
}

// ---------------- Kernel 5: combine r over chunks, y = r @ rp_w + rp_b ----------
__global__ __launch_bounds__(64, 1) void combine_kernel(
    const float* __restrict__ rc, const float* __restrict__ rp_w,
    const float* __restrict__ rp_b, float* __restrict__ yv) {
  int b = blockIdx.x, j = threadIdx.x;
  float r = 0.f;
#pragma unroll 8
  for (int cc = 0; cc < NG; ++cc) r += rc[((size_t)b * NG + cc) * HH + j];
  __shared__ float rs[HH];
  rs[j] = r;
  __syncthreads();
  float yj = rp_b[j];
#pragma unroll
  for (int h = 0; h < HH; ++h) yj = fmaf(rs[h], rp_w[h * HH + j], yj);
  yv[b * HH + j] = yj;
}

// ---------------- Kernel 6: output GEMM ----------------
__global__ __launch_bounds__(256, 2) void out_kernel(
    const float* __restrict__ yv, const float* __restrict__ out_w,
    const float* __restrict__ out_b, float* __restrict__ out) {
  __shared__ float ys[BB * HH];
  for (int i = threadIdx.x; i < BB * HH; i += 256) ys[i] = yv[i];
  __syncthreads();

  int v = blockIdx.x * 256 + threadIdx.x;
  if (v >= VV) return;

  float acc[BB];
  float ob = out_b[v];
#pragma unroll
  for (int b = 0; b < BB; ++b) acc[b] = ob;

  for (int h = 0; h < HH; ++h) {
    float w = out_w[(size_t)h * VV + v];
#pragma unroll
    for (int b = 0; b < BB; ++b) acc[b] = fmaf(ys[b * HH + h], w, acc[b]);
  }
#pragma unroll
  for (int b = 0; b < BB; ++b) out[(size_t)b * VV + v] = acc[b];
}

// ---------------- launch ----------------
extern "C" void kernel_launch(void* const* d_in, const int* in_sizes, int n_in,
                              void* d_out, int out_size, void* d_ws, size_t ws_size,
                              hipStream_t stream) {
  (void)in_sizes; (void)n_in; (void)out_size; (void)ws_size;
  const int*   seq   = (const int*)d_in[0];
  const int*   rp    = (const int*)d_in[1];
  const float* embed = (const float*)d_in[2];
  const float* w1    = (const float*)d_in[3];
  const float* b1    = (const float*)d_in[4];
  const float* w2    = (const float*)d_in[5];
  const float* b2    = (const float*)d_in[6];
  const float* ln_g  = (const float*)d_in[7];
  const float* ln_b  = (const float*)d_in[8];
  const float* rp_w  = (const float*)d_in[9];
  const float* rp_b  = (const float*)d_in[10];
  const float* out_w = (const float*)d_in[11];
  const float* out_b = (const float*)d_in[12];
  float* out = (float*)d_out;

  // workspace layout (~68.6 MB)
  float* h_all = (float*)d_ws;                               // B*L*H
  float* beta  = h_all + (size_t)BB * LL * HH;               // B*L
  float* Ng    = beta + (size_t)BB * LL;                     // B*NG*H*H (32 MB, N^T)
  float* Qg    = Ng + (size_t)BB * NG * HH * HH;             // B*NG*H
  float* rcv   = Qg + (size_t)BB * NG * HH;                  // B*NG*H
  float* yv    = rcv + (size_t)BB * NG * HH;                 // B*H
  unsigned short* w1b = (unsigned short*)(yv + (size_t)BB * HH);  // 128*64 bf16
  unsigned short* w2b = w1b + 8192;                               // 64*128 bf16

  prep_kernel<<<64, 256, 0, stream>>>(w1, w2, w1b, w2b);
  encoder_kernel<<<BB * LL / 64, 64, 0, stream>>>(seq, embed, w1b, b1, w2b, b2,
                                                  ln_g, ln_b, h_all, beta);
  gram_n_kernel<<<dim3(NG, BB), 64, 0, stream>>>(h_all, beta, Ng);
  boundary_kernel<<<BB, 64, 0, stream>>>(h_all, Ng, rp, Qg);
  chunk_scan_kernel<<<dim3(NG, BB), 64, 0, stream>>>(h_all, beta, Qg, rcv);
  combine_kernel<<<BB, 64, 0, stream>>>(rcv, rp_w, rp_b, yv);
  out_kernel<<<(VV + 255) / 256, 256, 0, stream>>>(yv, out_w, out_b, out);
}

// Round 6
// 220.720 us; speedup vs baseline: 1.0658x; 1.0658x over previous
//
#include <hip/hip_runtime.h>

#define HH 64
#define VV 50257
#define BB 32
#define LL 4096

constexpr float LN_EPS_F = 1e-5f;
constexpr float DELTA_EPS_F = 1e-6f;

constexpr int CS = 64;       // chunk size (steps per chunk)
constexpr int NG = LL / CS;  // 64 chunks per batch

typedef float f32x4 __attribute__((ext_vector_type(4)));
typedef float f32x2 __attribute__((ext_vector_type(2)));
typedef short bf16x8 __attribute__((ext_vector_type(8)));
union U16x8 { uint4 u; bf16x8 v; unsigned short s[8]; };

__device__ __forceinline__ unsigned short f2bf(float f) {
  union { float f; unsigned u; } v; v.f = f;
  unsigned r = v.u + 0x7fff + ((v.u >> 16) & 1);  // RNE
  return (unsigned short)(r >> 16);
}

// v_cvt_pk_bf16_f32: lo16 = bf16(a), hi16 = bf16(b); RNE — bit-identical to f2bf.
__device__ __forceinline__ unsigned cvt_pk_bf16(float a, float b) {
  unsigned r;
  asm("v_cvt_pk_bf16_f32 %0, %1, %2" : "=v"(r) : "v"(a), "v"(b));
  return r;
}

// hi/lo split for a pair: hp = packed bf16 hi parts, lp = packed bf16 residuals.
__device__ __forceinline__ void split2(float a, float b, unsigned& hp, unsigned& lp) {
  hp = cvt_pk_bf16(a, b);
  float ha = __uint_as_float(hp << 16);
  float hb = __uint_as_float(hp & 0xffff0000u);
  lp = cvt_pk_bf16(a - ha, b - hb);
}

// ---------------- DPP wave reduction (sum of 64 lanes -> lane 63) ----------------
template <int CTRL>
__device__ __forceinline__ float dpp_add(float x) {
  int t = __builtin_amdgcn_update_dpp(0, __float_as_int(x), CTRL, 0xF, 0xF, true);
  return x + __int_as_float(t);
}

__device__ __forceinline__ float wave_sum_lane63(float x) {
  x = dpp_add<0x111>(x);
  x = dpp_add<0x112>(x);
  x = dpp_add<0x114>(x);
  x = dpp_add<0x118>(x);
  x = dpp_add<0x142>(x);
  x = dpp_add<0x143>(x);
  return x;
}

__device__ __forceinline__ float readlane_f(float x, int lane) {
  return __int_as_float(__builtin_amdgcn_readlane(__float_as_int(x), lane));
}

// ---------------- Kernel 0: bf16 weight prep ----------------
__global__ __launch_bounds__(256) void prep_kernel(
    const float* __restrict__ w1, const float* __restrict__ w2,
    unsigned short* __restrict__ w1b, unsigned short* __restrict__ w2b) {
  int i = blockIdx.x * 256 + threadIdx.x;  // 0..16383
  if (i < 8192) {
    int jj = i >> 6, h = i & 63;
    w1b[i] = f2bf(w1[h * 128 + jj]);
  } else {
    int k = i - 8192;
    int h = k >> 7, jj = k & 127;
    w2b[k] = f2bf(w2[jj * 64 + h]);
  }
}

// ---------------- Kernel 1: encoder via bf16 MFMA ----------------
// r14: LDS 27.9K -> 17.9K for residency-quantization fix (2048 blocks = 8/CU; at
// 5 resident/CU the 8 blocks take 2 rounds; at >=8 resident 1 round).
// act_l (17.4 KB) replaced by a per-ks 64x40-short column chunk (5.1 KB) written
// from the acc1 epilogue and consumed immediately by GEMM2's ks-th MFMA set.
// Numerics identical: same values, same accumulation order over ks.
__global__ __launch_bounds__(64, 1) void encoder_kernel(
    const int* __restrict__ seq, const float* __restrict__ embed,
    const unsigned short* __restrict__ w1b, const float* __restrict__ b1,
    const unsigned short* __restrict__ w2b, const float* __restrict__ b2,
    const float* __restrict__ ln_g, const float* __restrict__ ln_b,
    float* __restrict__ h_all, float* __restrict__ beta) {
  __shared__ __align__(16) char pool[16640];  // e_l(9216)+chunk(5120); x_l(16640) aliases
  unsigned short (*e_l)[72] = reinterpret_cast<unsigned short (*)[72]>(pool);
  unsigned short (*chunk)[40] = reinterpret_cast<unsigned short (*)[40]>(pool + 9216);
  float (*x_l)[65] = reinterpret_cast<float (*)[65]>(pool);
  __shared__ float2 gb_l[64];
  __shared__ float b1_l[128], b2_l[64];

  int lane = threadIdx.x;
  int q = lane >> 4, l = lane & 15;
  int base = blockIdx.x * 64;
  int s = seq[base + lane];

  {
    const float4* ep = reinterpret_cast<const float4*>(embed + (size_t)s * HH);
#pragma unroll
    for (int i = 0; i < 8; ++i) {
      float4 va = ep[2 * i], vb = ep[2 * i + 1];
      uint4 u;
      u.x = cvt_pk_bf16(va.x, va.y);
      u.y = cvt_pk_bf16(va.z, va.w);
      u.z = cvt_pk_bf16(vb.x, vb.y);
      u.w = cvt_pk_bf16(vb.z, vb.w);
      *(uint4*)&e_l[lane][8 * i] = u;
    }
  }
  gb_l[lane] = make_float2(ln_g[lane], ln_b[lane]);
  b1_l[lane] = b1[lane];
  b1_l[64 + lane] = b1[64 + lane];
  b2_l[lane] = b2[lane];

  bf16x8 af1[8][2];
#pragma unroll
  for (int mi = 0; mi < 8; ++mi)
#pragma unroll
    for (int ks = 0; ks < 2; ++ks) {
      U16x8 t;
      t.u = *(const uint4*)(w1b + (mi * 16 + l) * 64 + ks * 32 + q * 8);
      af1[mi][ks] = t.v;
    }

  __syncthreads();

  f32x4 acc1[8][4];
#pragma unroll
  for (int mi = 0; mi < 8; ++mi)
#pragma unroll
    for (int nt = 0; nt < 4; ++nt) acc1[mi][nt] = (f32x4){0.f, 0.f, 0.f, 0.f};

#pragma unroll
  for (int ks = 0; ks < 2; ++ks) {
    bf16x8 bfr[4];
#pragma unroll
    for (int nt = 0; nt < 4; ++nt) {
      U16x8 t;
      t.u = *(const uint4*)&e_l[nt * 16 + l][ks * 32 + q * 8];
      bfr[nt] = t.v;
    }
#pragma unroll
    for (int mi = 0; mi < 8; ++mi)
#pragma unroll
      for (int nt = 0; nt < 4; ++nt)
        acc1[mi][nt] = __builtin_amdgcn_mfma_f32_16x16x32_bf16(
            af1[mi][ks], bfr[nt], acc1[mi][nt], 0, 0, 0);
  }

  bf16x8 bf2[4][4];
#pragma unroll
  for (int nt = 0; nt < 4; ++nt)
#pragma unroll
    for (int ks = 0; ks < 4; ++ks) {
      U16x8 t;
      t.u = *(const uint4*)(w2b + (nt * 16 + l) * 128 + ks * 32 + q * 8);
      bf2[nt][ks] = t.v;
    }

  // ---- fused epilogue + GEMM2, one 32-col act chunk at a time (chunk != e_l region)
  f32x4 acc2[4][4];
#pragma unroll
  for (int mt = 0; mt < 4; ++mt)
#pragma unroll
    for (int nt = 0; nt < 4; ++nt) acc2[mt][nt] = (f32x4){0.f, 0.f, 0.f, 0.f};

#pragma unroll
  for (int ks2 = 0; ks2 < 4; ++ks2) {
#pragma unroll
    for (int mm = 0; mm < 2; ++mm) {
      int mi = 2 * ks2 + mm;
      int jj0 = mi * 16 + q * 4;
      int col = mm * 16 + q * 4;
#pragma unroll
      for (int nt = 0; nt < 4; ++nt) {
        int tok = nt * 16 + l;
        float v0 = fmaxf(acc1[mi][nt][0] + b1_l[jj0 + 0], 0.f);
        float v1 = fmaxf(acc1[mi][nt][1] + b1_l[jj0 + 1], 0.f);
        float v2 = fmaxf(acc1[mi][nt][2] + b1_l[jj0 + 2], 0.f);
        float v3 = fmaxf(acc1[mi][nt][3] + b1_l[jj0 + 3], 0.f);
        uint2 u;
        u.x = cvt_pk_bf16(v0, v1);
        u.y = cvt_pk_bf16(v2, v3);
        *(uint2*)&chunk[tok][col] = u;
      }
    }
    __syncthreads();

    bf16x8 afr[4];
#pragma unroll
    for (int mt = 0; mt < 4; ++mt) {
      U16x8 t;
      t.u = *(const uint4*)&chunk[mt * 16 + l][q * 8];
      afr[mt] = t.v;
    }
#pragma unroll
    for (int mt = 0; mt < 4; ++mt)
#pragma unroll
      for (int nt = 0; nt < 4; ++nt)
        acc2[mt][nt] = __builtin_amdgcn_mfma_f32_16x16x32_bf16(
            afr[mt], bf2[nt][ks2], acc2[mt][nt], 0, 0, 0);
    __syncthreads();  // chunk reads done before next iteration's writes / x_l alias
  }

#pragma unroll
  for (int mt = 0; mt < 4; ++mt)
#pragma unroll
    for (int nt = 0; nt < 4; ++nt) {
      int h = nt * 16 + l;
#pragma unroll
      for (int r = 0; r < 4; ++r) {
        int tok = mt * 16 + q * 4 + r;
        x_l[tok][h] = acc2[mt][nt][r] + b2_l[h];
      }
    }

  __syncthreads();

  float x[HH];
#pragma unroll
  for (int h = 0; h < HH; ++h) x[h] = x_l[lane][h];
  {
    const float4* ep = reinterpret_cast<const float4*>(embed + (size_t)s * HH);
#pragma unroll
    for (int i = 0; i < 16; ++i) {
      float4 v = ep[i];
      x[4 * i + 0] += v.x; x[4 * i + 1] += v.y;
      x[4 * i + 2] += v.z; x[4 * i + 3] += v.w;
    }
  }
  float sum = 0.f;
#pragma unroll
  for (int h = 0; h < HH; ++h) sum += x[h];
  float mu = sum * (1.f / HH);
  float vs = 0.f;
#pragma unroll
  for (int h = 0; h < HH; ++h) { float dx = x[h] - mu; vs = fmaf(dx, dx, vs); }
  float rstd = rsqrtf(vs * (1.f / HH) + LN_EPS_F);

  float ss = 0.f;
#pragma unroll
  for (int h = 0; h < HH; ++h) {
    float2 gb = gb_l[h];
    float o = fmaf((x[h] - mu) * rstd, gb.x, gb.y);
    ss = fmaf(o, o, ss);
    x[h] = o;
  }
  float4* hp = reinterpret_cast<float4*>(h_all + (size_t)(base + lane) * HH);
#pragma unroll
  for (int i = 0; i < 16; ++i)
    hp[i] = make_float4(x[4 * i + 0], x[4 * i + 1], x[4 * i + 2], x[4 * i + 3]);
  beta[base + lane] = 1.f / (ss + DELTA_EPS_F);
}

// ---------------- Kernel 2: Gram + m-recurrence + materialized N^T ----------------
// r14: residency-quantization fix (post-mortem r13: grid = 8 blocks/CU exactly;
// floor(160K/LDS) resident -> always 2 rounds of ~21us T_block regardless of the
// r10-r13 optimizations. Need >=8 resident: LDS <= 20KB AND VGPR <= 256).
//   * pA eliminated: N's A-operand (K^T rows) loaded directly from global with
//     frag-mapped transpose addresses (L2-warm 3rd read of the 16KB chunk),
//     split to hi/lo bf16 in registers — the r12 technique applied to N.
//   * Only pBh (m~^T, XOR-swizzled, r13-verified) remains in LDS, overlaid on
//     the dead Glp. LDS total: Glp 8448 + bl 256 = 8704 B -> LDS allows 18/CU.
//   * __launch_bounds__(64,2) pins VGPR <= 256 -> 2 waves/SIMD -> 8 blocks/CU
//     -> ONE round.
// Gram + recurrence numerics identical to r13 (verified).
__global__ __launch_bounds__(64, 2) void gram_n_kernel(
    const float* __restrict__ h_all, const float* __restrict__ beta,
    float* __restrict__ Ng) {
  __shared__ __align__(16) char smem[8704];
  float* Glp = reinterpret_cast<float*>(smem);      // 8448 B (dead after recurrence)
  char* pBh0 = smem;                                // overlay: 2 planes x 4096 B
  float* bl = reinterpret_cast<float*>(smem + 8448);  // 256 B

  int c = blockIdx.x, b = blockIdx.y, lane = threadIdx.x;
  int q = lane >> 4, l = lane & 15;
  const float* src = h_all + ((size_t)b * LL + c * CS) * HH;

  // ---- Gram frags direct from global, cvt_pk split
  bf16x8 ah[2][4], al_[2][4];
#pragma unroll
  for (int ks = 0; ks < 2; ++ks)
#pragma unroll
    for (int i = 0; i < 4; ++i) {
      const float* p = src + (i * 16 + l) * 64 + ks * 32 + q * 8;
      float4 va = *(const float4*)p, vb = *(const float4*)(p + 4);
      U16x8 hi, lo;
      split2(va.x, va.y, hi.u.x, lo.u.x);
      split2(va.z, va.w, hi.u.y, lo.u.y);
      split2(vb.x, vb.y, hi.u.z, lo.u.z);
      split2(vb.z, vb.w, hi.u.w, lo.u.w);
      ah[ks][i] = hi.v; al_[ks][i] = lo.v;
    }
  // t = L-1 is not a key: zero row 63 of K in the frags (held by l==15, i==3)
  if (c == NG - 1 && l == 15) {
#pragma unroll
    for (int ks = 0; ks < 2; ++ks) {
      ah[ks][3] = (bf16x8){0, 0, 0, 0, 0, 0, 0, 0};
      al_[ks][3] = (bf16x8){0, 0, 0, 0, 0, 0, 0, 0};
    }
  }

  bl[lane] = beta[(size_t)b * LL + c * CS + lane];

  // ---- m column loads issued BEFORE Gram compute (latency overlaps MFMAs)
  f32x2 m2[32];
#pragma unroll
  for (int t = 0; t < 32; ++t)
    m2[t] = (f32x2){src[(2 * t) * 64 + lane], src[(2 * t + 1) * 64 + lane]};
  if (c == NG - 1) m2[31].y = 0.f;

  // ---- Gram via split-bf16 MFMA (symmetric: lower tiles only, 60 MFMAs)
  f32x4 acc[4][4];
#pragma unroll
  for (int mi = 0; mi < 4; ++mi)
#pragma unroll
    for (int nt = 0; nt <= mi; ++nt) acc[mi][nt] = (f32x4){0.f, 0.f, 0.f, 0.f};

#pragma unroll
  for (int ks = 0; ks < 2; ++ks)
#pragma unroll
    for (int mi = 0; mi < 4; ++mi)
#pragma unroll
      for (int nt = 0; nt <= mi; ++nt) {
        acc[mi][nt] = __builtin_amdgcn_mfma_f32_16x16x32_bf16(ah[ks][mi], ah[ks][nt], acc[mi][nt], 0, 0, 0);
        acc[mi][nt] = __builtin_amdgcn_mfma_f32_16x16x32_bf16(ah[ks][mi], al_[ks][nt], acc[mi][nt], 0, 0, 0);
        acc[mi][nt] = __builtin_amdgcn_mfma_f32_16x16x32_bf16(al_[ks][mi], ah[ks][nt], acc[mi][nt], 0, 0, 0);
      }

  // ---- packed triangular Gl write (UNSCALED G; only t < s entries).
  // Row s=4g+i offsets: off(4g)=4g(2g+1); off(4g+i)=8g(g+1)+4(g+1)(i-1), i>=1.
#pragma unroll
  for (int mi = 0; mi < 4; ++mi) {
    int gg = 4 * mi + q;
    int e1 = 8 * gg * (gg + 1);
    int o0 = 4 * gg * (2 * gg + 1);
    int o1 = e1;
    int o2 = e1 + 4 * (gg + 1);
    int o3 = e1 + 8 * (gg + 1);
#pragma unroll
    for (int nt = 0; nt < mi; ++nt) {
      int t = nt * 16 + l;
      Glp[o0 + t] = acc[mi][nt][0];
      Glp[o1 + t] = acc[mi][nt][1];
      Glp[o2 + t] = acc[mi][nt][2];
      Glp[o3 + t] = acc[mi][nt][3];
    }
    {
      int t = mi * 16 + l;
      if (l < 4 * q)     Glp[o0 + t] = acc[mi][mi][0];
      if (l < 4 * q + 1) Glp[o1 + t] = acc[mi][mi][1];
      if (l < 4 * q + 2) Glp[o2 + t] = acc[mi][mi][2];
      if (l < 4 * q + 3) Glp[o3 + t] = acc[mi][mi][3];
    }
  }
  __syncthreads();  // Glp writes visible before recurrence reads

  // ---- rank-4 grouped m-recurrence (exact f32, pk-fma pairs), beta folded.
#pragma unroll
  for (int g = 15; g >= 0; --g) {
    int e1 = 8 * g * (g + 1);
    int o0 = 4 * g * (2 * g + 1);
    int o1 = e1;
    int o2 = e1 + 4 * (g + 1);
    int o3 = e1 + 8 * (g + 1);
    float4 C1 = *(const float4*)(Glp + o1 + 4 * g);  // row 4g+1 (x valid)
    float4 C2 = *(const float4*)(Glp + o2 + 4 * g);  // row 4g+2 (x,y valid)
    float4 C3 = *(const float4*)(Glp + o3 + 4 * g);  // row 4g+3 (x,y,z valid)
    float4 B4 = *(const float4*)(bl + 4 * g);        // beta[4g..4g+3] (uniform)

    float t3 = B4.w * m2[2 * g + 1].y;
    float v2 = fmaf(-C3.z, t3, m2[2 * g + 1].x);
    float t2 = B4.z * v2;
    float v1 = fmaf(-C2.y, t2, fmaf(-C3.y, t3, m2[2 * g].y));
    float t1 = B4.y * v1;
    float v0 = fmaf(-C1.x, t1, fmaf(-C2.x, t2, fmaf(-C3.x, t3, m2[2 * g].x)));
    float t0 = B4.x * v0;
    m2[2 * g] = (f32x2){t0, t1};
    m2[2 * g + 1] = (f32x2){t2, t3};
    f32x2 n0 = {-t0, -t0}, n1 = {-t1, -t1}, n2 = {-t2, -t2}, n3 = {-t3, -t3};

#pragma unroll
    for (int j = 0; j < g; ++j) {
      float4 R0 = *(const float4*)(Glp + o0 + 4 * j);
      float4 R1 = *(const float4*)(Glp + o1 + 4 * j);
      float4 R2 = *(const float4*)(Glp + o2 + 4 * j);
      float4 R3 = *(const float4*)(Glp + o3 + 4 * j);
      f32x2 a = m2[2 * j], d = m2[2 * j + 1];
      a = __builtin_elementwise_fma((f32x2){R0.x, R0.y}, n0, a);
      a = __builtin_elementwise_fma((f32x2){R1.x, R1.y}, n1, a);
      a = __builtin_elementwise_fma((f32x2){R2.x, R2.y}, n2, a);
      a = __builtin_elementwise_fma((f32x2){R3.x, R3.y}, n3, a);
      d = __builtin_elementwise_fma((f32x2){R0.z, R0.w}, n0, d);
      d = __builtin_elementwise_fma((f32x2){R1.z, R1.w}, n1, d);
      d = __builtin_elementwise_fma((f32x2){R2.z, R2.w}, n2, d);
      d = __builtin_elementwise_fma((f32x2){R3.z, R3.w}, n3, d);
      m2[2 * j] = a; m2[2 * j + 1] = d;
    }
  }
  // m2[] now holds m~ = beta_t * m_final[t] — the B operand N needs.

  __syncthreads();  // all Glp/bl reads done before pBh (overlay) writes

  // ---- N in 2 K-halves: A = K^T direct from global (transpose frag loads),
  //      B = m~^T half-buffer in LDS (XOR-swizzled). acc2 accumulates across halves.
  f32x4 acc2[4][4];
#pragma unroll
  for (int mi = 0; mi < 4; ++mi)
#pragma unroll
    for (int nt = 0; nt < 4; ++nt) acc2[mi][nt] = (f32x4){0.f, 0.f, 0.f, 0.f};

#pragma unroll
  for (int hf = 0; hf < 2; ++hf) {
    // issue A-frag transpose loads early (L2-warm): av[mi][r] = K[t][h],
    // t = hf*32 + q*8 + r, h = mi*16 + l
    float av[4][8];
#pragma unroll
    for (int mi = 0; mi < 4; ++mi)
#pragma unroll
      for (int r = 0; r < 8; ++r)
        av[mi][r] = src[(hf * 32 + q * 8 + r) * 64 + mi * 16 + l];

    // write pBh rows (row = h' = lane, cols t local 0..31), XOR-swizzled
#pragma unroll
    for (int i2 = 0; i2 < 8; ++i2) {
      int tt = hf * 16 + 2 * i2;
      unsigned h0, l0, h1, l1;
      split2(m2[tt].x, m2[tt].y, h0, l0);
      split2(m2[tt + 1].x, m2[tt + 1].y, h1, l1);
      unsigned boff = (unsigned)((lane * 64 + i2 * 8) ^ ((lane & 7) << 4));
      *(uint2*)(pBh0 + boff) = make_uint2(h0, h1);
      *(uint2*)(pBh0 + 4096 + boff) = make_uint2(l0, l1);
    }
    __syncthreads();  // pBh writes visible

    // t = 63 (hf==1, q==3, r==7) is not a key: zero in A
    if (c == NG - 1 && hf == 1 && q == 3) {
      av[0][7] = 0.f; av[1][7] = 0.f; av[2][7] = 0.f; av[3][7] = 0.f;
    }

    // build A frags (hi/lo) in registers
    bf16x8 ka[4], kl2[4];
#pragma unroll
    for (int mi = 0; mi < 4; ++mi) {
      U16x8 hi, lo;
      split2(av[mi][0], av[mi][1], hi.u.x, lo.u.x);
      split2(av[mi][2], av[mi][3], hi.u.y, lo.u.y);
      split2(av[mi][4], av[mi][5], hi.u.z, lo.u.z);
      split2(av[mi][6], av[mi][7], hi.u.w, lo.u.w);
      ka[mi] = hi.v; kl2[mi] = lo.v;
    }

    // read B frags from pBh
    bf16x8 bh[4], blo[4];
#pragma unroll
    for (int i = 0; i < 4; ++i) {
      unsigned bro = (unsigned)((((16 * i + l) * 64) + q * 16) ^ ((l & 7) << 4));
      U16x8 t;
      t.u = *(const uint4*)(pBh0 + bro);        bh[i] = t.v;
      t.u = *(const uint4*)(pBh0 + 4096 + bro); blo[i] = t.v;
    }

#pragma unroll
    for (int mi = 0; mi < 4; ++mi)
#pragma unroll
      for (int nt = 0; nt < 4; ++nt) {
        acc2[mi][nt] = __builtin_amdgcn_mfma_f32_16x16x32_bf16(ka[mi], bh[nt], acc2[mi][nt], 0, 0, 0);
        acc2[mi][nt] = __builtin_amdgcn_mfma_f32_16x16x32_bf16(ka[mi], blo[nt], acc2[mi][nt], 0, 0, 0);
        acc2[mi][nt] = __builtin_amdgcn_mfma_f32_16x16x32_bf16(kl2[mi], bh[nt], acc2[mi][nt], 0, 0, 0);
      }
    __syncthreads();  // half-hf B-frag reads done before next half's overwrite
  }

  // store TRANSPOSED: Ng[j*64 + h] = N[h][j]  (float4 over h)
  float* np = Ng + (((size_t)b * NG + c) << 12);
#pragma unroll
  for (int mi = 0; mi < 4; ++mi)
#pragma unroll
    for (int nt = 0; nt < 4; ++nt) {
      int h0 = mi * 16 + q * 4, hp = nt * 16 + l;
      float4 v;
      v.x = ((h0 + 0 == hp) ? 1.f : 0.f) - acc2[mi][nt][0];
      v.y = ((h0 + 1 == hp) ? 1.f : 0.f) - acc2[mi][nt][1];
      v.z = ((h0 + 2 == hp) ? 1.f : 0.f) - acc2[mi][nt][2];
      v.w = ((h0 + 3 == hp) ? 1.f : 0.f) - acc2[mi][nt][3];
      *(float4*)&np[hp * 64 + h0] = v;
    }
}

// ---------------- Kernel 3: boundary — LDS double-buffered matvec (unchanged) -----
__global__ __launch_bounds__(64, 1) void boundary_kernel(
    const float* __restrict__ h_all, const float* __restrict__ Ng,
    const int* __restrict__ read_pos_p, float* __restrict__ Qg) {
  __shared__ __align__(16) float nt0[64 * 64];
  __shared__ __align__(16) float nt1[64 * 64];
  __shared__ __align__(16) float ql[64];

  int b = blockIdx.x, lane = threadIdx.x;
  int rpv = read_pos_p[0];
  int pos = rpv < 0 ? rpv + LL : rpv;
  float Q = h_all[((size_t)b * LL + pos) * HH + lane];

  const float* Nb = Ng + ((size_t)b * NG << 12);

  auto load_chunk = [&](float* buf, int c) {
    const float* g = Nb + ((size_t)c << 12);
#pragma unroll
    for (int i = 0; i < 16; ++i)
      __builtin_amdgcn_global_load_lds(
          (const __attribute__((address_space(1))) unsigned*)(g + i * 256 + lane * 4),
          (__attribute__((address_space(3))) unsigned*)(buf + i * 256), 16, 0, 0);
  };

  auto step = [&](const float* buf, int c, bool last) {
    if (last) __builtin_amdgcn_s_waitcnt(0x0F70);  // vmcnt(0)
    else      __builtin_amdgcn_s_waitcnt(0x4F70);  // vmcnt(16)
    Qg[((size_t)b * NG + c) * HH + lane] = Q;
    ql[lane] = Q;
    float a0 = 0.f, a1 = 0.f, a2 = 0.f, a3 = 0.f;
#pragma unroll
    for (int j = 0; j < 64; j += 4) {
      float4 q4 = *(const float4*)&ql[j];  // uniform LDS broadcast
      a0 = fmaf(buf[(j + 0) * 64 + lane], q4.x, a0);
      a1 = fmaf(buf[(j + 1) * 64 + lane], q4.y, a1);
      a2 = fmaf(buf[(j + 2) * 64 + lane], q4.z, a2);
      a3 = fmaf(buf[(j + 3) * 64 + lane], q4.w, a3);
    }
    Q = (a0 + a1) + (a2 + a3);
  };

  load_chunk(nt1, NG - 1);
  load_chunk(nt0, NG - 2);

#pragma unroll 1
  for (int c = NG - 1; c >= 1; c -= 2) {
    step(nt1, c, false);
    __builtin_amdgcn_s_waitcnt(0xC07F);  // lgkmcnt(0)
    if (c >= 3) load_chunk(nt1, c - 2);
    step(nt0, c - 1, c == 1);
    __builtin_amdgcn_s_waitcnt(0xC07F);
    if (c >= 3) load_chunk(nt0, c - 3);
  }
}

// ---------------- Kernel 4 (phase 3): parallel within-chunk r accumulation -------
__global__ __launch_bounds__(64, 1) void chunk_scan_kernel(
    const float* __restrict__ h_all, const float* __restrict__ beta,
    const float* __restrict__ Qg, float* __restrict__ rc) {
  int c = blockIdx.x, b = blockIdx.y, j = threadIdx.x;
  const float* hb = h_all + (size_t)b * LL * HH;
  const float* betab = beta + (size_t)b * LL;

  float P = Qg[((size_t)b * NG + c) * HH + j];
  float r = 0.f;

  float kk[CS];
#pragma unroll
  for (int i = 0; i < CS; ++i) kk[i] = hb[((size_t)(c * CS + i)) * HH + j];
  float bv = betab[c * CS + j];

  bool last = (c == NG - 1);
#pragma unroll
  for (int i = CS - 1; i >= 0; --i) {
    float k = kk[i];
    float bt = readlane_f(bv, i);
    float m = k * P;
    float s = wave_sum_lane63(m);
    float d = readlane_f(s, 63);
    if (i == CS - 1 && last) d = 0.f;
    r = fmaf(d, k, r);
    P = fmaf(-(bt * d), k, P);
  }
  rc[((size_t)b * NG + c) * HH + j] = r;
}

// ---------------- Kernel 5: combine r over chunks, y = r @ rp_w + rp_b ----------
__global__ __launch_bounds__(64, 1) void combine_kernel(
    const float* __restrict__ rc, const float* __restrict__ rp_w,
    const float* __restrict__ rp_b, float* __restrict__ yv) {
  int b = blockIdx.x, j = threadIdx.x;
  float r = 0.f;
#pragma unroll 8
  for (int cc = 0; cc < NG; ++cc) r += rc[((size_t)b * NG + cc) * HH + j];
  __shared__ float rs[HH];
  rs[j] = r;
  __syncthreads();
  float yj = rp_b[j];
#pragma unroll
  for (int h = 0; h < HH; ++h) yj = fmaf(rs[h], rp_w[h * HH + j], yj);
  yv[b * HH + j] = yj;
}

// ---------------- Kernel 6: output GEMM ----------------
__global__ __launch_bounds__(256, 2) void out_kernel(
    const float* __restrict__ yv, const float* __restrict__ out_w,
    const float* __restrict__ out_b, float* __restrict__ out) {
  __shared__ float ys[BB * HH];
  for (int i = threadIdx.x; i < BB * HH; i += 256) ys[i] = yv[i];
  __syncthreads();

  int v = blockIdx.x * 256 + threadIdx.x;
  if (v >= VV) return;

  float acc[BB];
  float ob = out_b[v];
#pragma unroll
  for (int b = 0; b < BB; ++b) acc[b] = ob;

  for (int h = 0; h < HH; ++h) {
    float w = out_w[(size_t)h * VV + v];
#pragma unroll
    for (int b = 0; b < BB; ++b) acc[b] = fmaf(ys[b * HH + h], w, acc[b]);
  }
#pragma unroll
  for (int b = 0; b < BB; ++b) out[(size_t)b * VV + v] = acc[b];
}

// ---------------- launch ----------------
extern "C" void kernel_launch(void* const* d_in, const int* in_sizes, int n_in,
                              void* d_out, int out_size, void* d_ws, size_t ws_size,
                              hipStream_t stream) {
  (void)in_sizes; (void)n_in; (void)out_size; (void)ws_size;
  const int*   seq   = (const int*)d_in[0];
  const int*   rp    = (const int*)d_in[1];
  const float* embed = (const float*)d_in[2];
  const float* w1    = (const float*)d_in[3];
  const float* b1    = (const float*)d_in[4];
  const float* w2    = (const float*)d_in[5];
  const float* b2    = (const float*)d_in[6];
  const float* ln_g  = (const float*)d_in[7];
  const float* ln_b  = (const float*)d_in[8];
  const float* rp_w  = (const float*)d_in[9];
  const float* rp_b  = (const float*)d_in[10];
  const float* out_w = (const float*)d_in[11];
  const float* out_b = (const float*)d_in[12];
  float* out = (float*)d_out;

  // workspace layout (~68.6 MB)
  float* h_all = (float*)d_ws;                               // B*L*H
  float* beta  = h_all + (size_t)BB * LL * HH;               // B*L
  float* Ng    = beta + (size_t)BB * LL;                     // B*NG*H*H (32 MB, N^T)
  float* Qg    = Ng + (size_t)BB * NG * HH * HH;             // B*NG*H
  float* rcv   = Qg + (size_t)BB * NG * HH;                  // B*NG*H
  float* yv    = rcv + (size_t)BB * NG * HH;                 // B*H
  unsigned short* w1b = (unsigned short*)(yv + (size_t)BB * HH);  // 128*64 bf16
  unsigned short* w2b = w1b + 8192;                               // 64*128 bf16

  prep_kernel<<<64, 256, 0, stream>>>(w1, w2, w1b, w2b);
  encoder_kernel<<<BB * LL / 64, 64, 0, stream>>>(seq, embed, w1b, b1, w2b, b2,
                                                  ln_g, ln_b, h_all, beta);
  gram_n_kernel<<<dim3(NG, BB), 64, 0, stream>>>(h_all, beta, Ng);
  boundary_kernel<<<BB, 64, 0, stream>>>(h_all, Ng, rp, Qg);
  chunk_scan_kernel<<<dim3(NG, BB), 64, 0, stream>>>(h_all, beta, Qg, rcv);
  combine_kernel<<<BB, 64, 0, stream>>>(rcv, rp_w, rp_b, yv);
  out_kernel<<<(VV + 255) / 256, 256, 0, stream>>>(yv, out_w, out_b, out);
}